// Round 9
// baseline (105.248 us; speedup 1.0000x reference)
//
#include <hip/hip_runtime.h>
#include <cstdint>
#include <cstddef>

#define MROWS 1024
#define NCOLS 4096
#define KCAP 32

typedef unsigned long long u64;
typedef unsigned int u32;

// Order-preserving float->u32 map (total order, matches score order exactly).
__device__ inline u32 fkey(u32 b) { return (b & 0x80000000u) ? ~b : (b | 0x80000000u); }

// key = (ord << 22) | ((1023-row) << 12) | (4095-col)   (54 bits used)
__device__ inline int key_col(u64 k) { return (NCOLS - 1) - (int)(k & 0xFFFull); }
__device__ inline int key_row(u64 k) { return (MROWS - 1) - (int)((k >> 12) & 0x3FFull); }

// single-wave LDS ordering fence: wait LDS only, do NOT drain vmcnt
#define WAVE_FENCE() __asm__ volatile("s_waitcnt lgkmcnt(0)" ::: "memory")

__device__ inline float wave_sum_f(float v) {
    #pragma unroll
    for (int off = 32; off >= 1; off >>= 1)
        v += __shfl_xor(v, off, 64);
    return v;
}
__device__ inline u64 wave_max_u64(u64 v) {
    #pragma unroll
    for (int off = 32; off >= 1; off >>= 1) {
        u64 o = __shfl_xor(v, off, 64);
        v = o > v ? o : v;
    }
    return v;
}
__device__ inline u64 umax64(u64 a, u64 b) { return a > b ? a : b; }

// ---------------- K1: per-row threshold key-set + exp-sum ---------------------
// Wave-per-row, ZERO block barriers, 256 workgroups. The match only needs each
// row's stored keys to be an exact PREFIX of the row's descending key order;
// {keys: score > T} is such a prefix for any T (fkey monotone, ties cannot
// straddle T). Ladder 2.5/2.9/3.4/4.2 on overflow (count monotone in T; rare
// retry reloads the row from L2). Short/empty prefix is still exact (row
// exhausts -> exact fallback in K2). N(0,1): E[count@2.5] ~ 25.6.
__global__ __launch_bounds__(256, 4) void k_prep(const float* __restrict__ s,
                                                 float* __restrict__ rowsum,
                                                 u64* __restrict__ keys_g) {
    __shared__ u64 list[4][KCAP];
    __shared__ u32 cnts[4];
    int w = threadIdx.x >> 6, lane = threadIdx.x & 63;
    int r = blockIdx.x * 4 + w;

    const float4* s4 = (const float4*)(s + (size_t)r * NCOLS);
    u64 rowpart = (u64)(MROWS - 1 - r) << 12;
    if (lane == 0) cnts[w] = 0u;
    WAVE_FENCE();

    float acc = 0.0f;
    #pragma unroll
    for (int j = 0; j < 16; ++j) {
        float4 v = s4[lane + j * 64];
        acc += __expf(v.x) + __expf(v.y) + __expf(v.z) + __expf(v.w);
        int c0 = 4 * (lane + j * 64);
        if (v.x > 2.5f) { u32 sl = atomicAdd(&cnts[w], 1u); if (sl < KCAP)
            list[w][sl] = ((u64)fkey(__float_as_uint(v.x)) << 22) | rowpart | (u64)(NCOLS - 1 - (c0 + 0)); }
        if (v.y > 2.5f) { u32 sl = atomicAdd(&cnts[w], 1u); if (sl < KCAP)
            list[w][sl] = ((u64)fkey(__float_as_uint(v.y)) << 22) | rowpart | (u64)(NCOLS - 1 - (c0 + 1)); }
        if (v.z > 2.5f) { u32 sl = atomicAdd(&cnts[w], 1u); if (sl < KCAP)
            list[w][sl] = ((u64)fkey(__float_as_uint(v.z)) << 22) | rowpart | (u64)(NCOLS - 1 - (c0 + 2)); }
        if (v.w > 2.5f) { u32 sl = atomicAdd(&cnts[w], 1u); if (sl < KCAP)
            list[w][sl] = ((u64)fkey(__float_as_uint(v.w)) << 22) | rowpart | (u64)(NCOLS - 1 - (c0 + 3)); }
    }
    acc = wave_sum_f(acc);
    if (lane == 0) rowsum[r] = acc;
    WAVE_FENCE();
    u32 n = cnts[w];

    // ladder retries (P ~ 9% @attempt1, ~1e-12 beyond): reload row (L2-hot)
    for (int att = 1; att < 4; ++att) {
        if (n <= KCAP) break;
        float T = att == 1 ? 2.9f : att == 2 ? 3.4f : 4.2f;
        if (lane == 0) cnts[w] = 0u;
        WAVE_FENCE();
        #pragma unroll 4
        for (int j = 0; j < 16; ++j) {
            float4 v = s4[lane + j * 64];
            int c0 = 4 * (lane + j * 64);
            if (v.x > T) { u32 sl = atomicAdd(&cnts[w], 1u); if (sl < KCAP)
                list[w][sl] = ((u64)fkey(__float_as_uint(v.x)) << 22) | rowpart | (u64)(NCOLS - 1 - (c0 + 0)); }
            if (v.y > T) { u32 sl = atomicAdd(&cnts[w], 1u); if (sl < KCAP)
                list[w][sl] = ((u64)fkey(__float_as_uint(v.y)) << 22) | rowpart | (u64)(NCOLS - 1 - (c0 + 1)); }
            if (v.z > T) { u32 sl = atomicAdd(&cnts[w], 1u); if (sl < KCAP)
                list[w][sl] = ((u64)fkey(__float_as_uint(v.z)) << 22) | rowpart | (u64)(NCOLS - 1 - (c0 + 2)); }
            if (v.w > T) { u32 sl = atomicAdd(&cnts[w], 1u); if (sl < KCAP)
                list[w][sl] = ((u64)fkey(__float_as_uint(v.w)) << 22) | rowpart | (u64)(NCOLS - 1 - (c0 + 3)); }
        }
        WAVE_FENCE();
        n = cnts[w];
    }
    if (n > KCAP) n = 0;               // ladder failed (adversarial): empty prefix
    if (lane < KCAP)
        keys_g[(size_t)r * KCAP + lane] = (lane < n) ? list[w][lane] : 0ull;
}

// ---------------- K2: block 0 = match (parallel rounds); rest = policy --------
// Match: dominant-edge rounds, 512 threads x 2 rows, 32 keys/row in REGISTERS
// (cap 256 at 512 thr -- the 1024-thr variant capped at 128 and risked spill).
// Distinct u64 keys + exact-prefix sets => identical to serial greedy; colbest
// tagged by round so stale submissions auto-lose.
__global__ __launch_bounds__(512, 1) void k_policy_match(const float* __restrict__ s,
                                                         const int* __restrict__ cont,
                                                         const int* __restrict__ prev,
                                                         const float* __restrict__ rowsum,
                                                         const u64* __restrict__ keys_g,
                                                         float* __restrict__ policy,
                                                         float* __restrict__ actions) {
    __shared__ u64 colbest[NCOLS];             // 32 KiB (match only)
    __shared__ u32 coldone[NCOLS / 32];        // 512 B
    __shared__ u32 rowdone[MROWS / 32];        // 128 B
    __shared__ float act[MROWS];               // 4 KiB
    __shared__ float fredf[8];

    int t = threadIdx.x;
    int wid = t >> 6, lane = t & 63;

    if (blockIdx.x != 0) {
        // ---------------- policy row write (512 thr, 2 float4/thr) ------------
        int r = blockIdx.x - 1;
        const float4* srow4 = (const float4*)(s + (size_t)r * NCOLS);
        float4 v0 = srow4[t], v1 = srow4[t + 512];   // fly during the reduce
        float sv = rowsum[t] + rowsum[t + 512];
        sv = wave_sum_f(sv);
        if (lane == 0) fredf[wid] = sv;
        __syncthreads();
        float g = 0.0f;
        #pragma unroll
        for (int i = 0; i < 8; ++i) g += fredf[i];   // same order every block
        float inv = 1.0f / g;
        float4* prow4 = (float4*)(policy + (size_t)r * NCOLS);
        float4 p;
        p.x = __expf(v0.x) * inv; p.y = __expf(v0.y) * inv;
        p.z = __expf(v0.z) * inv; p.w = __expf(v0.w) * inv;
        prow4[t] = p;
        p.x = __expf(v1.x) * inv; p.y = __expf(v1.y) * inv;
        p.z = __expf(v1.z) * inv; p.w = __expf(v1.w) * inv;
        prow4[t + 512] = p;
        return;
    }

    // ---------------- match: thread t owns rows t and t+512 -------------------
    #pragma unroll
    for (int i = 0; i < 8; ++i) colbest[t + i * 512] = 0ull;
    if (t < 128) coldone[t] = 0u;
    if (t < 32) rowdone[t] = 0u;
    __syncthreads();   // zeroing ordered before the atomics below

    int r0 = t, r1 = t + 512;
    int c0f = cont[r0], c1f = cont[r1];
    int p0 = prev[r0], p1 = prev[r1];
    act[r0] = c0f ? (float)p0 : -1.0f;
    act[r1] = c1f ? (float)p1 : -1.0f;
    if (c0f) {
        atomicOr(&rowdone[r0 >> 5], 1u << (r0 & 31));
        atomicOr(&coldone[p0 >> 5], 1u << (p0 & 31));
    }
    if (c1f) {
        atomicOr(&rowdone[r1 >> 5], 1u << (r1 & 31));
        atomicOr(&coldone[p1 >> 5], 1u << (p1 & 31));
    }
    bool act0 = (c0f == 0), act1 = (c1f == 0);

    u64 k0[KCAP], k1[KCAP];
    {
        const u64* g0 = keys_g + (size_t)r0 * KCAP;
        const u64* g1 = keys_g + (size_t)r1 * KCAP;
        #pragma unroll
        for (int k = 0; k < KCAP; ++k) { k0[k] = g0[k]; k1[k] = g1[k]; }
    }
    __syncthreads();

    for (int round = 1; round < 400; ++round) {
        u64 tag = (u64)round << 54;
        bool sub0 = false, sub1 = false;
        u64 best0 = 0ull, best1 = 0ull;
        if (act0) {
            #pragma unroll
            for (int h = 0; h < 2; ++h) {
                u32 cw[16];
                #pragma unroll
                for (int k = 0; k < 16; ++k) {
                    int c = key_col(k0[h * 16 + k]);   // dead key -> col 4095, safe
                    cw[k] = coldone[c >> 5];
                }
                #pragma unroll
                for (int k = 0; k < 16; ++k) {
                    int c = key_col(k0[h * 16 + k]);
                    if ((cw[k] >> (c & 31)) & 1u) k0[h * 16 + k] = 0ull;
                    best0 = umax64(best0, k0[h * 16 + k]);
                }
            }
            if (best0 == 0ull) act0 = false;     // exhausted -> exact fallback
            else {
                sub0 = true;
                #pragma unroll
                for (int k = 0; k < KCAP; ++k)
                    if (k0[k] != 0ull)
                        atomicMax((u64*)&colbest[key_col(k0[k])], tag | k0[k]);
            }
        }
        if (act1) {
            #pragma unroll
            for (int h = 0; h < 2; ++h) {
                u32 cw[16];
                #pragma unroll
                for (int k = 0; k < 16; ++k) {
                    int c = key_col(k1[h * 16 + k]);
                    cw[k] = coldone[c >> 5];
                }
                #pragma unroll
                for (int k = 0; k < 16; ++k) {
                    int c = key_col(k1[h * 16 + k]);
                    if ((cw[k] >> (c & 31)) & 1u) k1[h * 16 + k] = 0ull;
                    best1 = umax64(best1, k1[h * 16 + k]);
                }
            }
            if (best1 == 0ull) act1 = false;
            else {
                sub1 = true;
                #pragma unroll
                for (int k = 0; k < KCAP; ++k)
                    if (k1[k] != 0ull)
                        atomicMax((u64*)&colbest[key_col(k1[k])], tag | k1[k]);
            }
        }
        __syncthreads();                          // submissions visible
        u64 cb0 = sub0 ? colbest[key_col(best0)] : 0ull;
        u64 cb1 = sub1 ? colbest[key_col(best1)] : 0ull;
        if (sub0 && cb0 == (tag | best0)) {
            int c = key_col(best0);
            u32 old = atomicOr(&coldone[c >> 5], 1u << (c & 31));
            if (!(old & (1u << (c & 31)))) {
                act[r0] = (float)c;
                atomicOr(&rowdone[r0 >> 5], 1u << (r0 & 31));
                act0 = false;
            }
        }
        if (sub1 && cb1 == (tag | best1)) {
            int c = key_col(best1);
            u32 old = atomicOr(&coldone[c >> 5], 1u << (c & 31));
            if (!(old & (1u << (c & 31)))) {
                act[r1] = (float)c;
                atomicOr(&rowdone[r1 >> 5], 1u << (r1 & 31));
                act1 = false;
            }
        }
        int left = __syncthreads_count((act0 || act1) ? 1 : 0);  // commit barrier
        if (left == 0) break;
    }
    __syncthreads();

    // ---- exact-greedy fallback for exhausted rows (rare) ---------------------
    if (t < 64) {
        u32 miss = (t < 32) ? ~rowdone[t] : 0u;
        if (__ballot(miss != 0u) != 0ull) {
            for (int guard = 0; guard < 1200; ++guard) {
                u64 best = 0ull;
                for (int rr = 0; rr < MROWS; ++rr) {
                    if ((rowdone[rr >> 5] >> (rr & 31)) & 1u) continue;
                    const float* srow = s + (size_t)rr * NCOLS;
                    u64 rp = (u64)(MROWS - 1 - rr) << 12;
                    for (int c = t; c < NCOLS; c += 64) {
                        if ((coldone[c >> 5] >> (c & 31)) & 1u) continue;
                        u64 kk2 = ((u64)fkey(__float_as_uint(srow[c])) << 22) | rp |
                                  (u64)(NCOLS - 1 - c);
                        best = umax64(best, kk2);
                    }
                }
                best = wave_max_u64(best);
                if (best == 0ull) break;
                if (t == 0) {
                    int row = key_row(best), col = key_col(best);
                    rowdone[row >> 5] |= 1u << (row & 31);
                    coldone[col >> 5] |= 1u << (col & 31);
                    act[row] = (float)col;
                }
                WAVE_FENCE();
            }
        }
    }
    __syncthreads();
    actions[t] = act[t];
    actions[t + 512] = act[t + 512];
}

extern "C" void kernel_launch(void* const* d_in, const int* in_sizes, int n_in,
                              void* d_out, int out_size, void* d_ws, size_t ws_size,
                              hipStream_t stream) {
    (void)in_sizes; (void)n_in; (void)out_size; (void)ws_size;
    const float* scores = (const float*)d_in[0];
    const int* cont = (const int*)d_in[1];
    const int* prev = (const int*)d_in[2];
    float* out = (float*)d_out;
    float* actions = out;
    float* policy = out + MROWS;

    char* ws = (char*)d_ws;
    float* rowsum = (float*)(ws + 0);            // 1024 f
    u64* keys32 = (u64*)(ws + 8192);             // 1024*32 u64 = 256 KiB

    k_prep<<<MROWS / 4, 256, 0, stream>>>(scores, rowsum, keys32);
    k_policy_match<<<MROWS + 1, 512, 0, stream>>>(scores, cont, prev, rowsum,
                                                  keys32, policy, actions);
}